// Round 10
// baseline (287.986 us; speedup 1.0000x reference)
//
#include <hip/hip_runtime.h>

typedef short s16x8 __attribute__((ext_vector_type(8)));
typedef short s16x4 __attribute__((ext_vector_type(4)));
typedef float f32x4 __attribute__((ext_vector_type(4)));
typedef float f32x16 __attribute__((ext_vector_type(16)));

__device__ __forceinline__ unsigned short f2bf(float f) {
  unsigned u = __float_as_uint(f);
  u += 0x7fffu + ((u >> 16) & 1u);
  return (unsigned short)(u >> 16);
}
__device__ __forceinline__ float bf2f(unsigned short h) {
  return __uint_as_float(((unsigned)h) << 16);
}

#define GLOAD_LDS16(g, l)                                          \
  __builtin_amdgcn_global_load_lds(                                \
      (const __attribute__((address_space(1))) void*)(g),          \
      (__attribute__((address_space(3))) void*)(l), 16, 0, 0)

// ---------------- prep kernels ----------------

__global__ __launch_bounds__(256) void cvt_x_bf16(const float* __restrict__ in,
                                                  unsigned short* __restrict__ out) {
  int i = (blockIdx.x * 256 + threadIdx.x) * 4;
  float4 v = *(const float4*)(in + i);
  ushort4 o;
  o.x = f2bf(v.x); o.y = f2bf(v.y); o.z = f2bf(v.z); o.w = f2bf(v.w);
  *(ushort4*)(out + i) = o;
}

// W[R][C] fp32 -> Wt[C][R] bf16
__global__ __launch_bounds__(256) void transpose_w(const float* __restrict__ W,
                                                   unsigned short* __restrict__ Wt,
                                                   int R, int C) {
  __shared__ float tile[32][33];
  int c0 = blockIdx.x * 32, r0 = blockIdx.y * 32;
  int x = threadIdx.x, ty = threadIdx.y;
  for (int yy = ty; yy < 32; yy += 8)
    tile[yy][x] = W[(size_t)(r0 + yy) * C + c0 + x];
  __syncthreads();
  for (int yy = ty; yy < 32; yy += 8)
    Wt[(size_t)(c0 + yy) * R + r0 + x] = f2bf(tile[x][yy]);
}

// ---------------- GEMM v8: 256x128 block, wave tile 128x64 ----------------
// C[M][N] = A[M][K] * Bt[N][K]^T + bias. 256 threads = 4 waves (2M x 2N),
// wave tile 128x64 = acc[4][2] f32x16, 32x32x16 MFMA.
// WHY: rounds 6-9 showed four different schedules all pinned at MfmaUtil
// 24-28% -> the limiter is the LDS-pipe cycles per MFMA, not scheduling.
// Wave tile 128x64 cuts ds_read_b128 per MFMA from (2+2)/4=1.0 to
// (4+2)/8=0.75 and staging bytes/MFMA from 500 to 375 (A-tile shared by both
// N-waves, B-tile by both M-waves, over 2x the MFMAs).
// BK=32, LDS = 2 bufs x (A 256x32 + B 128x32) bf16 = 48KB -> 2-3 desynced
// blocks/CU. Proven r6 2-phase skeleton: one __syncthreads per K-tile, next
// tile's 6 gload_lds issued right after, flying during compute.
// 64B-row swizzle (r5-proven, at the free 2-way floor): 16B chunk c of row r
// stored at c ^ ((r>>1)&3) via pre-swizzled global source; read offset
// (l5*16 + ks*32) ^ (((lm>>1)&3)<<4).
// Grids tail-perfect: QKV 32x24=768=3x256, proj 32x8=256=1x256.
// MODE 0: f32 out. MODE 1: bf16; n0>=2048 blocks (V third of QKV) store
// TRANSPOSED direct to vtr[(b*16+h)*64+d][tok] (no transpose_v dispatch).

template <int MODE>
__global__ __launch_bounds__(256, 2) void gemm_bt(const unsigned short* __restrict__ A,
                                                  const unsigned short* __restrict__ Bt,
                                                  const float* __restrict__ bias,
                                                  void* __restrict__ Cout,
                                                  unsigned short* __restrict__ vtr,
                                                  int M, int N, int K) {
  __shared__ __align__(16) unsigned short As[2][256 * 32];
  __shared__ __align__(16) unsigned short Bs[2][128 * 32];

  const int tid  = threadIdx.x;
  const int lane = tid & 63;
  const int w    = tid >> 6;    // 0..3
  const int lm   = lane & 31;   // frag row/col within 32
  const int l5   = lane >> 5;   // k-half selector
  const int wr   = w >> 1;      // 0..1: M rows [wr*128, wr*128+128)
  const int wc   = w & 1;       // 0..1: N cols [wc*64, wc*64+64)
  const int m0   = blockIdx.x * 256;  // x = m: XCD-stable A tiles
  const int n0   = blockIdx.y * 128;

  f32x16 acc[4][2];
  for (int i = 0; i < 4; i++)
    for (int j = 0; j < 2; j++)
      for (int r = 0; r < 16; r++) acc[i][j][r] = 0.f;

  const int srow = tid >> 2;                                // staging row 0..63
  const int scb  = (((tid & 3) ^ ((srow >> 1) & 3)) * 8);   // pre-swizzled source col
  const unsigned short* Ap = A  + (size_t)(m0 + srow) * K + scb;
  const unsigned short* Bp = Bt + (size_t)(n0 + srow) * K + scb;

  // A: 4 instrs/wave cover rows 0..255 (64 rows each); B: 2 instrs (128 rows).
  // Dest linear: wave w writes 1KB (16 rows of 64B) at i*2048 + w*512 shorts.
#define STAGE_G(bb, t)                                                        \
  do {                                                                        \
    for (int i = 0; i < 4; i++)                                               \
      GLOAD_LDS16(Ap + (size_t)(i * 64) * K + (t) * 32,                       \
                  &As[bb][i * 2048 + w * 512]);                               \
    for (int i = 0; i < 2; i++)                                               \
      GLOAD_LDS16(Bp + (size_t)(i * 64) * K + (t) * 32,                       \
                  &Bs[bb][i * 2048 + w * 512]);                               \
  } while (0)

  const int rx = ((lm >> 1) & 3) << 4;  // read-side XOR (bytes)
  const int nt = K >> 5;                // 32 for K=1024

  STAGE_G(0, 0);
  int cur = 0;
  for (int t = 0; t < nt; t++) {
    __syncthreads();  // drains vmcnt: tile t landed; all waves done with buf cur^1
    if (t + 1 < nt) STAGE_G(cur ^ 1, t + 1);

    const char* Ab = (const char*)As[cur];
    const char* Bb = (const char*)Bs[cur];
    s16x8 af[4][2], bfr[2][2];
    for (int i = 0; i < 4; i++)
      for (int ks = 0; ks < 2; ks++)
        af[i][ks] = *(const s16x8*)(Ab + (wr * 128 + i * 32 + lm) * 64 +
                                    ((l5 * 16 + ks * 32) ^ rx));
    for (int j = 0; j < 2; j++)
      for (int ks = 0; ks < 2; ks++)
        bfr[j][ks] = *(const s16x8*)(Bb + (wc * 64 + j * 32 + lm) * 64 +
                                     ((l5 * 16 + ks * 32) ^ rx));
    __builtin_amdgcn_s_setprio(1);
    for (int ks = 0; ks < 2; ks++)
      for (int i = 0; i < 4; i++)
        for (int j = 0; j < 2; j++)
          acc[i][j] = __builtin_amdgcn_mfma_f32_32x32x16_bf16(af[i][ks], bfr[j][ks],
                                                              acc[i][j], 0, 0, 0);
    __builtin_amdgcn_s_setprio(0);
    cur ^= 1;
  }
#undef STAGE_G

  // epilogue: C/D layout col=lane&31, row=(r&3)+8*(r>>2)+4*l5
  if (MODE == 1 && n0 >= 2048) {
    // V third: store transposed to vtr[b*1024 + (col-2048)][token]
    const int bidx = m0 >> 11;  // batch (m0 multiple of 256)
    for (int j = 0; j < 2; j++) {
      int col = n0 + wc * 64 + j * 32 + lm;
      float bc = bias[col];
      size_t vrow = (size_t)((bidx << 10) + (col - 2048)) * 2048;
      for (int i = 0; i < 4; i++) {
        int tb = (m0 & 2047) + wr * 128 + i * 32 + l5 * 4;
        for (int g = 0; g < 4; g++) {
          ushort4 o;
          o.x = f2bf(acc[i][j][g * 4 + 0] + bc);
          o.y = f2bf(acc[i][j][g * 4 + 1] + bc);
          o.z = f2bf(acc[i][j][g * 4 + 2] + bc);
          o.w = f2bf(acc[i][j][g * 4 + 3] + bc);
          *(ushort4*)(vtr + vrow + tb + 8 * g) = o;
        }
      }
    }
  } else {
    for (int j = 0; j < 2; j++) {
      int col = n0 + wc * 64 + j * 32 + lm;
      float bc = bias[col];
      for (int i = 0; i < 4; i++) {
        int rowb = m0 + wr * 128 + i * 32 + l5 * 4;
        for (int r = 0; r < 16; r++) {
          int row = rowb + (r & 3) + 8 * (r >> 2);
          float v = acc[i][j][r] + bc;
          if (MODE == 1)
            ((unsigned short*)Cout)[(size_t)row * N + col] = f2bf(v);
          else
            ((float*)Cout)[(size_t)row * N + col] = v;
        }
      }
    }
  }
}

// ---------------- flash attention v11 (unchanged) ----------------
// 4 waves x 32 q, all-K32 MFMA path, dbuf gload_lds prefetch, kt-loop
// unrolled x2, v_cvt_pk_bf16_f32 P-pack, setprio around MFMA clusters.

__global__ __launch_bounds__(256, 4) void attn_flash(const unsigned short* __restrict__ qkv,
                                                     const unsigned short* __restrict__ vt,
                                                     unsigned short* __restrict__ y) {
  const int T = 2048, C3 = 3072;
  const int bh = blockIdx.x & 63;
  const int qt = blockIdx.x >> 6;
  const int b  = bh >> 4;
  const int h  = bh & 15;
  const int q0 = qt * 128;

  const int tid  = threadIdx.x;
  const int lane = tid & 63;
  const int w    = tid >> 6;  // 0..3, wave owns q rows q0 + w*32 + [0,32)
  const int lr   = lane & 15;
  const int quad = lane >> 4;

  __shared__ __align__(16) unsigned short Ks[2][64][64];  // keys x d, swizzled, K-row-permuted
  __shared__ __align__(16) unsigned short Vs[2][64][64];  // d x keys (V^T), swizzled

  // Q as B-operand: qf[j][c] covers q rows w*32 + j*16 + lr, d-chunk c.
  s16x8 qf[2][2];
  const float QSC = 0.18033688f;  // log2(e)/sqrt(64)
  for (int j = 0; j < 2; j++)
    for (int c = 0; c < 2; c++) {
      const unsigned short* qp =
          qkv + (size_t)(b * T + q0 + w * 32 + j * 16 + lr) * C3 + h * 64 + c * 32 + quad * 8;
      s16x8 t = *(const s16x8*)qp;
      s16x8 o;
      for (int e = 0; e < 8; e++)
        o[e] = (short)f2bf(bf2f((unsigned short)t[e]) * QSC);
      qf[j][c] = o;
    }

  s16x8 ones;
  for (int e = 0; e < 8; e++) ones[e] = (short)0x3F80;  // bf16 1.0

  f32x4 O[2][4];   // [q-subtile j][d-tile]; row=q(quad*4+r), col=d(lr)
  f32x4 Lacc[2];   // row-sum accumulator, same row layout as O
  for (int j = 0; j < 2; j++) {
    for (int dt = 0; dt < 4; dt++) O[j][dt] = f32x4{0.f, 0.f, 0.f, 0.f};
    Lacc[j] = f32x4{0.f, 0.f, 0.f, 0.f};
  }

  const int srow = tid >> 3;                       // 0..31
  // pre-swizzled global source col (shorts): lane slot (l&7) XOR row&7
  const int scol = (((tid & 7) ^ (srow & 7)) * 8);
  // K-row permutation within each 32-key chunk: storage row -> key
  const int kperm = (((srow & 12) << 1) | ((srow >> 4) << 2) | (srow & 3));

  const unsigned short* kbase = qkv + (size_t)(b * T) * C3 + 1024 + (size_t)h * 64;
  const unsigned short* vbase = vt + (size_t)(bh * 64) * 2048;
  const unsigned short* kp0 = kbase + (size_t)(kperm)      * C3 + scol;  // rows 0..31
  const unsigned short* kp1 = kbase + (size_t)(32 + kperm) * C3 + scol;  // rows 32..63
  const unsigned short* vp0 = vbase + (size_t)(srow)      * 2048 + scol;
  const unsigned short* vp1 = vbase + (size_t)(srow + 32) * 2048 + scol;

#define STAGE_KV(bb)                                                         \
  do {                                                                       \
    GLOAD_LDS16(kp0, &Ks[bb][w * 8][0]);                                     \
    GLOAD_LDS16(kp1, &Ks[bb][w * 8 + 32][0]);                                \
    GLOAD_LDS16(vp0, &Vs[bb][w * 8][0]);                                     \
    GLOAD_LDS16(vp1, &Vs[bb][w * 8 + 32][0]);                                \
    kp0 += (size_t)64 * C3; kp1 += (size_t)64 * C3;                          \
    vp0 += 64; vp1 += 64;                                                    \
  } while (0)

  const int rswz = (lr & 7) << 4;  // read-side XOR (row&7 == lr&7 for all reads)

#define COMPUTE(bb)                                                              \
  do {                                                                           \
    const char* KsB = (const char*)&Ks[bb][0][0];                                \
    const char* VsB = (const char*)&Vs[bb][0][0];                                \
    for (int ch = 0; ch < 2; ch++) {                                             \
      const char* krowA = KsB + (ch * 32 + lr) * 128;                            \
      const char* krowB = KsB + (ch * 32 + 16 + lr) * 128;                       \
      s16x8 kA0 = *(const s16x8*)(krowA + ((quad * 16) ^ rswz));                 \
      s16x8 kA1 = *(const s16x8*)(krowA + ((64 + quad * 16) ^ rswz));            \
      s16x8 kB0 = *(const s16x8*)(krowB + ((quad * 16) ^ rswz));                 \
      s16x8 kB1 = *(const s16x8*)(krowB + ((64 + quad * 16) ^ rswz));            \
      s16x8 vf[4];                                                               \
      for (int dt = 0; dt < 4; dt++)                                             \
        vf[dt] = *(const s16x8*)(VsB + (dt * 16 + lr) * 128 +                    \
                                 ((ch * 64 + quad * 16) ^ rswz));                \
      for (int j = 0; j < 2; j++) {                                              \
        f32x4 Sa = f32x4{0.f, 0.f, 0.f, 0.f};                                    \
        f32x4 Sb = f32x4{0.f, 0.f, 0.f, 0.f};                                    \
        __builtin_amdgcn_s_setprio(1);                                           \
        Sa = __builtin_amdgcn_mfma_f32_16x16x32_bf16(kA0, qf[j][0], Sa, 0, 0, 0);\
        Sa = __builtin_amdgcn_mfma_f32_16x16x32_bf16(kA1, qf[j][1], Sa, 0, 0, 0);\
        Sb = __builtin_amdgcn_mfma_f32_16x16x32_bf16(kB0, qf[j][0], Sb, 0, 0, 0);\
        Sb = __builtin_amdgcn_mfma_f32_16x16x32_bf16(kB1, qf[j][1], Sb, 0, 0, 0);\
        __builtin_amdgcn_s_setprio(0);                                           \
        float p0 = __builtin_amdgcn_exp2f(Sa[0]);                                \
        float p1 = __builtin_amdgcn_exp2f(Sa[1]);                                \
        float p2 = __builtin_amdgcn_exp2f(Sa[2]);                                \
        float p3 = __builtin_amdgcn_exp2f(Sa[3]);                                \
        float p4 = __builtin_amdgcn_exp2f(Sb[0]);                                \
        float p5 = __builtin_amdgcn_exp2f(Sb[1]);                                \
        float p6 = __builtin_amdgcn_exp2f(Sb[2]);                                \
        float p7 = __builtin_amdgcn_exp2f(Sb[3]);                                \
        union { unsigned u[4]; s16x8 v; } pk;                                    \
        asm("v_cvt_pk_bf16_f32 %0, %1, %2" : "=v"(pk.u[0]) : "v"(p0), "v"(p1));  \
        asm("v_cvt_pk_bf16_f32 %0, %1, %2" : "=v"(pk.u[1]) : "v"(p2), "v"(p3));  \
        asm("v_cvt_pk_bf16_f32 %0, %1, %2" : "=v"(pk.u[2]) : "v"(p4), "v"(p5));  \
        asm("v_cvt_pk_bf16_f32 %0, %1, %2" : "=v"(pk.u[3]) : "v"(p6), "v"(p7));  \
        __builtin_amdgcn_s_setprio(1);                                           \
        Lacc[j] = __builtin_amdgcn_mfma_f32_16x16x32_bf16(pk.v, ones, Lacc[j],   \
                                                          0, 0, 0);              \
        for (int dt = 0; dt < 4; dt++)                                           \
          O[j][dt] = __builtin_amdgcn_mfma_f32_16x16x32_bf16(pk.v, vf[dt],       \
                                                             O[j][dt], 0, 0, 0); \
        __builtin_amdgcn_s_setprio(0);                                           \
      }                                                                          \
    }                                                                            \
  } while (0)

  STAGE_KV(0);
  for (int kt2 = 0; kt2 < 16; kt2++) {
    __syncthreads();   // buf0's loads visible; all waves done reading buf1
    STAGE_KV(1);       // tile 2*kt2+1 (always valid)
    COMPUTE(0);        // tile 2*kt2
    __syncthreads();   // buf1's loads visible; all waves done reading buf0
    if (kt2 < 15) STAGE_KV(0);  // tile 2*kt2+2
    COMPUTE(1);        // tile 2*kt2+1
  }
#undef STAGE_KV
#undef COMPUTE

  // epilogue: Lacc rows align with O rows -> no cross-lane traffic
  for (int j = 0; j < 2; j++) {
    for (int r = 0; r < 4; r++) {
      float inv = 1.f / Lacc[j][r];
      int row = b * T + q0 + w * 32 + j * 16 + quad * 4 + r;
      for (int dt = 0; dt < 4; dt++) {
        int col = h * 64 + dt * 16 + lr;
        y[(size_t)row * 1024 + col] = f2bf(O[j][dt][r] * inv);
      }
    }
  }
}

// ---------------- launch ----------------

extern "C" void kernel_launch(void* const* d_in, const int* in_sizes, int n_in,
                              void* d_out, int out_size, void* d_ws, size_t ws_size,
                              hipStream_t stream) {
  const float* x  = (const float*)d_in[0];
  const float* Wa = (const float*)d_in[1];
  const float* ba = (const float*)d_in[2];
  const float* Wp = (const float*)d_in[3];
  const float* bp = (const float*)d_in[4];
  float* out = (float*)d_out;

  char* ws = (char*)d_ws;
  unsigned short* xb  = (unsigned short*)ws;                 // 16 MB: x bf16, later y
  unsigned short* Wat = (unsigned short*)(ws + 16777216);    // 6 MB
  unsigned short* Wpt = (unsigned short*)(ws + 23068672);    // 2 MB
  unsigned short* qkv = (unsigned short*)(ws + 25165824);    // 48 MB (V third unused)
  unsigned short* vtr = (unsigned short*)(ws + 75497472);    // 16 MB

  cvt_x_bf16<<<8192, 256, 0, stream>>>(x, xb);
  transpose_w<<<dim3(96, 32), dim3(32, 8), 0, stream>>>(Wa, Wat, 1024, 3072);
  transpose_w<<<dim3(32, 32), dim3(32, 8), 0, stream>>>(Wp, Wpt, 1024, 1024);

  // 256x128 blocks, wave tile 128x64: QKV grid 32x24 = 768 (3 generations);
  // V third straight to vtr (transposed in-epilogue)
  gemm_bt<1><<<dim3(32, 24), 256, 0, stream>>>(xb, Wat, ba, qkv, vtr, 8192, 3072, 1024);

  attn_flash<<<1024, 256, 0, stream>>>(qkv, vtr, xb);

  gemm_bt<0><<<dim3(32, 8), 256, 0, stream>>>(xb, Wpt, bp, out, nullptr, 8192, 1024, 1024);
}

// Round 11
// 263.928 us; speedup vs baseline: 1.0912x; 1.0912x over previous
//
#include <hip/hip_runtime.h>

typedef short s16x8 __attribute__((ext_vector_type(8)));
typedef short s16x4 __attribute__((ext_vector_type(4)));
typedef float f32x4 __attribute__((ext_vector_type(4)));
typedef float f32x16 __attribute__((ext_vector_type(16)));

__device__ __forceinline__ unsigned short f2bf(float f) {
  unsigned u = __float_as_uint(f);
  u += 0x7fffu + ((u >> 16) & 1u);
  return (unsigned short)(u >> 16);
}
__device__ __forceinline__ float bf2f(unsigned short h) {
  return __uint_as_float(((unsigned)h) << 16);
}

#define GLOAD_LDS16(g, l)                                          \
  __builtin_amdgcn_global_load_lds(                                \
      (const __attribute__((address_space(1))) void*)(g),          \
      (__attribute__((address_space(3))) void*)(l), 16, 0, 0)

// ---------------- fused prep kernel ----------------
// One dispatch replaces {cvt_x_bf16, transpose_w(Wa), transpose_w(Wp)}:
// blocks [0,8192)           : x f32 -> bf16 (4 elems/thread)
// blocks [8192,11264)       : Wa [1024][3072] -> Wat [3072][1024] bf16
// blocks [11264,12288)      : Wp [1024][1024] -> Wpt [1024][1024] bf16
// Rationale: ~70us of wall time is inter-dispatch gaps (sum of dispatch
// durations ~194us vs 265us total over 6 launches); fusing prep removes 2
// gaps with identical inner bodies.

__global__ __launch_bounds__(256) void prep(const float* __restrict__ x,
                                            unsigned short* __restrict__ xb,
                                            const float* __restrict__ Wa,
                                            unsigned short* __restrict__ Wat,
                                            const float* __restrict__ Wp,
                                            unsigned short* __restrict__ Wpt) {
  __shared__ float tile[32][33];
  const int bid = blockIdx.x;
  const int tid = threadIdx.x;
  if (bid < 8192) {
    int i = (bid * 256 + tid) * 4;
    float4 v = *(const float4*)(x + i);
    ushort4 o;
    o.x = f2bf(v.x); o.y = f2bf(v.y); o.z = f2bf(v.z); o.w = f2bf(v.w);
    *(ushort4*)(xb + i) = o;
    return;
  }
  const float* W;
  unsigned short* Wt;
  int R = 1024, C, c0, r0;
  if (bid < 11264) {
    int b = bid - 8192;          // 3072 blocks = 96 x 32
    W = Wa; Wt = Wat; C = 3072;
    c0 = (b % 96) * 32; r0 = (b / 96) * 32;
  } else {
    int b = bid - 11264;         // 1024 blocks = 32 x 32
    W = Wp; Wt = Wpt; C = 1024;
    c0 = (b % 32) * 32; r0 = (b / 32) * 32;
  }
  const int tx = tid & 31, ty = tid >> 5;
  for (int yy = ty; yy < 32; yy += 8)
    tile[yy][tx] = W[(size_t)(r0 + yy) * C + c0 + tx];
  __syncthreads();
  for (int yy = ty; yy < 32; yy += 8)
    Wt[(size_t)(c0 + yy) * R + r0 + tx] = f2bf(tile[tx][yy]);
}

// ---------------- GEMM v5 (r7, best-total config) ----------------
// C[M][N] = A[M][K] * Bt[N][K]^T + bias. 128x128 tile, BK=32, 32x32x16 MFMA
// (2x2 frags/wave). LDS [128][32] shorts, swizzle chunk c ^= ((r>>1)&3) via
// pre-swizzled global source (gload_lds dest linear) -> bank floor on b128
// frag reads. THREE buffers, 2-deep prefetch, counted s_waitcnt vmcnt(4) +
// raw s_barrier (never drain vmcnt to 0 in the main loop). 48KB LDS ->
// 3 desynced blocks/CU; this desync capacity is what six alternative
// schedules (r8 8-phase, r9 BK=64, r10 128x64 wave tile) all lost — they
// regressed 8-28%, so the engine is frozen here (~670 TF at K=1024, near
// this structure family's ceiling per the m102 shape curve).
// MODE 0: f32 out. MODE 1: bf16 out; n0>=2048 blocks (V third of QKV) store
// TRANSPOSED direct to vtr[(b*16+h)*64+d][tok] (kills transpose_v).

template <int MODE>
__global__ __launch_bounds__(256) void gemm_bt(const unsigned short* __restrict__ A,
                                               const unsigned short* __restrict__ Bt,
                                               const float* __restrict__ bias,
                                               void* __restrict__ Cout,
                                               unsigned short* __restrict__ vtr,
                                               int M, int N, int K) {
  __shared__ __align__(16) unsigned short As[3][128 * 32];
  __shared__ __align__(16) unsigned short Bs[3][128 * 32];

  const int tid  = threadIdx.x;
  const int lane = tid & 63;
  const int w    = tid >> 6;
  const int lm   = lane & 31;   // frag row/col within 32
  const int l5   = lane >> 5;   // k-half selector
  const int wm   = (w >> 1) * 64;
  const int wn   = (w & 1) * 64;
  const int m0   = blockIdx.x * 128;  // x = m: XCD-stable A tiles
  const int n0   = blockIdx.y * 128;

  f32x16 acc[2][2];
  for (int i = 0; i < 2; i++)
    for (int j = 0; j < 2; j++)
      for (int r = 0; r < 16; r++) acc[i][j][r] = 0.f;

  const int srow = tid >> 2;                                // staging LDS row 0..63
  const int scb  = (((tid & 3) ^ ((srow >> 1) & 3)) * 8);   // pre-swizzled source col
  const unsigned short* Ap = A  + (size_t)(m0 + srow) * K + scb;
  const unsigned short* Bp = Bt + (size_t)(n0 + srow) * K + scb;

#define STAGE_G(bb, kk)                                                  \
  do {                                                                   \
    GLOAD_LDS16(Ap + (kk), &As[bb][w * 512]);                            \
    GLOAD_LDS16(Ap + (size_t)64 * K + (kk), &As[bb][2048 + w * 512]);    \
    GLOAD_LDS16(Bp + (kk), &Bs[bb][w * 512]);                            \
    GLOAD_LDS16(Bp + (size_t)64 * K + (kk), &Bs[bb][2048 + w * 512]);    \
  } while (0)

  const int rx = ((lm >> 1) & 3) << 4;  // read-side XOR (bytes): row>>1 & 3

  STAGE_G(0, 0);
  STAGE_G(1, 32);
  int cur = 0;
  for (int kk = 0; kk < K; kk += 32) {
    // counted wait: tile kk landed; tile kk+1's 4 loads may stay in flight
    if (kk + 32 < K)
      asm volatile("s_waitcnt vmcnt(4)" ::: "memory");
    else
      asm volatile("s_waitcnt vmcnt(0)" ::: "memory");
    __builtin_amdgcn_s_barrier();
    __builtin_amdgcn_sched_barrier(0);

    if (kk + 64 < K) {
      int nb = cur + 2; if (nb >= 3) nb -= 3;
      STAGE_G(nb, kk + 64);
    }

    const char* Ab = (const char*)As[cur];
    const char* Bb = (const char*)Bs[cur];
    s16x8 af[2][2], bfr[2][2];
    for (int i = 0; i < 2; i++)
      for (int ks = 0; ks < 2; ks++)
        af[i][ks] = *(const s16x8*)(Ab + (wm + i * 32 + lm) * 64 +
                                    (((l5 * 16 + ks * 32)) ^ rx));
    for (int j = 0; j < 2; j++)
      for (int ks = 0; ks < 2; ks++)
        bfr[j][ks] = *(const s16x8*)(Bb + (wn + j * 32 + lm) * 64 +
                                     (((l5 * 16 + ks * 32)) ^ rx));
    for (int ks = 0; ks < 2; ks++)
      for (int i = 0; i < 2; i++)
        for (int j = 0; j < 2; j++)
          acc[i][j] = __builtin_amdgcn_mfma_f32_32x32x16_bf16(af[i][ks], bfr[j][ks],
                                                              acc[i][j], 0, 0, 0);
    cur += 1; if (cur >= 3) cur -= 3;
  }
#undef STAGE_G

  // epilogue: C/D layout col=lane&31, row=(r&3)+8*(r>>2)+4*l5
  if (MODE == 1 && n0 >= 2048) {
    // V third: store transposed to vtr[b*1024 + (col-2048)][token]
    const int bidx = m0 >> 11;  // batch (m0 aligned to 128)
    for (int j = 0; j < 2; j++) {
      int col = n0 + wn + j * 32 + lm;
      float bc = bias[col];
      size_t vrow = (size_t)((bidx << 10) + (col - 2048)) * 2048;
      for (int i = 0; i < 2; i++) {
        int tb = (m0 & 2047) + wm + i * 32 + l5 * 4;
        for (int g = 0; g < 4; g++) {
          ushort4 o;
          o.x = f2bf(acc[i][j][g * 4 + 0] + bc);
          o.y = f2bf(acc[i][j][g * 4 + 1] + bc);
          o.z = f2bf(acc[i][j][g * 4 + 2] + bc);
          o.w = f2bf(acc[i][j][g * 4 + 3] + bc);
          *(ushort4*)(vtr + vrow + tb + 8 * g) = o;
        }
      }
    }
  } else {
    for (int j = 0; j < 2; j++) {
      int col = n0 + wn + j * 32 + lm;
      float bc = bias[col];
      for (int i = 0; i < 2; i++) {
        int rowb = m0 + wm + i * 32 + l5 * 4;
        for (int r = 0; r < 16; r++) {
          int row = rowb + (r & 3) + 8 * (r >> 2);
          float v = acc[i][j][r] + bc;
          if (MODE == 1)
            ((unsigned short*)Cout)[(size_t)row * N + col] = f2bf(v);
          else
            ((float*)Cout)[(size_t)row * N + col] = v;
        }
      }
    }
  }
}

// ---------------- flash attention v11 (unchanged) ----------------
// 4 waves x 32 q, all-K32 MFMA path, dbuf gload_lds prefetch, kt-loop
// unrolled x2, v_cvt_pk_bf16_f32 P-pack, setprio around MFMA clusters.

__global__ __launch_bounds__(256, 4) void attn_flash(const unsigned short* __restrict__ qkv,
                                                     const unsigned short* __restrict__ vt,
                                                     unsigned short* __restrict__ y) {
  const int T = 2048, C3 = 3072;
  const int bh = blockIdx.x & 63;
  const int qt = blockIdx.x >> 6;
  const int b  = bh >> 4;
  const int h  = bh & 15;
  const int q0 = qt * 128;

  const int tid  = threadIdx.x;
  const int lane = tid & 63;
  const int w    = tid >> 6;  // 0..3, wave owns q rows q0 + w*32 + [0,32)
  const int lr   = lane & 15;
  const int quad = lane >> 4;

  __shared__ __align__(16) unsigned short Ks[2][64][64];  // keys x d, swizzled, K-row-permuted
  __shared__ __align__(16) unsigned short Vs[2][64][64];  // d x keys (V^T), swizzled

  // Q as B-operand: qf[j][c] covers q rows w*32 + j*16 + lr, d-chunk c.
  s16x8 qf[2][2];
  const float QSC = 0.18033688f;  // log2(e)/sqrt(64)
  for (int j = 0; j < 2; j++)
    for (int c = 0; c < 2; c++) {
      const unsigned short* qp =
          qkv + (size_t)(b * T + q0 + w * 32 + j * 16 + lr) * C3 + h * 64 + c * 32 + quad * 8;
      s16x8 t = *(const s16x8*)qp;
      s16x8 o;
      for (int e = 0; e < 8; e++)
        o[e] = (short)f2bf(bf2f((unsigned short)t[e]) * QSC);
      qf[j][c] = o;
    }

  s16x8 ones;
  for (int e = 0; e < 8; e++) ones[e] = (short)0x3F80;  // bf16 1.0

  f32x4 O[2][4];   // [q-subtile j][d-tile]; row=q(quad*4+r), col=d(lr)
  f32x4 Lacc[2];   // row-sum accumulator, same row layout as O
  for (int j = 0; j < 2; j++) {
    for (int dt = 0; dt < 4; dt++) O[j][dt] = f32x4{0.f, 0.f, 0.f, 0.f};
    Lacc[j] = f32x4{0.f, 0.f, 0.f, 0.f};
  }

  const int srow = tid >> 3;                       // 0..31
  // pre-swizzled global source col (shorts): lane slot (l&7) XOR row&7
  const int scol = (((tid & 7) ^ (srow & 7)) * 8);
  // K-row permutation within each 32-key chunk: storage row -> key
  const int kperm = (((srow & 12) << 1) | ((srow >> 4) << 2) | (srow & 3));

  const unsigned short* kbase = qkv + (size_t)(b * T) * C3 + 1024 + (size_t)h * 64;
  const unsigned short* vbase = vt + (size_t)(bh * 64) * 2048;
  const unsigned short* kp0 = kbase + (size_t)(kperm)      * C3 + scol;  // rows 0..31
  const unsigned short* kp1 = kbase + (size_t)(32 + kperm) * C3 + scol;  // rows 32..63
  const unsigned short* vp0 = vbase + (size_t)(srow)      * 2048 + scol;
  const unsigned short* vp1 = vbase + (size_t)(srow + 32) * 2048 + scol;

#define STAGE_KV(bb)                                                         \
  do {                                                                       \
    GLOAD_LDS16(kp0, &Ks[bb][w * 8][0]);                                     \
    GLOAD_LDS16(kp1, &Ks[bb][w * 8 + 32][0]);                                \
    GLOAD_LDS16(vp0, &Vs[bb][w * 8][0]);                                     \
    GLOAD_LDS16(vp1, &Vs[bb][w * 8 + 32][0]);                                \
    kp0 += (size_t)64 * C3; kp1 += (size_t)64 * C3;                          \
    vp0 += 64; vp1 += 64;                                                    \
  } while (0)

  const int rswz = (lr & 7) << 4;  // read-side XOR (row&7 == lr&7 for all reads)

#define COMPUTE(bb)                                                              \
  do {                                                                           \
    const char* KsB = (const char*)&Ks[bb][0][0];                                \
    const char* VsB = (const char*)&Vs[bb][0][0];                                \
    for (int ch = 0; ch < 2; ch++) {                                             \
      const char* krowA = KsB + (ch * 32 + lr) * 128;                            \
      const char* krowB = KsB + (ch * 32 + 16 + lr) * 128;                       \
      s16x8 kA0 = *(const s16x8*)(krowA + ((quad * 16) ^ rswz));                 \
      s16x8 kA1 = *(const s16x8*)(krowA + ((64 + quad * 16) ^ rswz));            \
      s16x8 kB0 = *(const s16x8*)(krowB + ((quad * 16) ^ rswz));                 \
      s16x8 kB1 = *(const s16x8*)(krowB + ((64 + quad * 16) ^ rswz));            \
      s16x8 vf[4];                                                               \
      for (int dt = 0; dt < 4; dt++)                                             \
        vf[dt] = *(const s16x8*)(VsB + (dt * 16 + lr) * 128 +                    \
                                 ((ch * 64 + quad * 16) ^ rswz));                \
      for (int j = 0; j < 2; j++) {                                              \
        f32x4 Sa = f32x4{0.f, 0.f, 0.f, 0.f};                                    \
        f32x4 Sb = f32x4{0.f, 0.f, 0.f, 0.f};                                    \
        __builtin_amdgcn_s_setprio(1);                                           \
        Sa = __builtin_amdgcn_mfma_f32_16x16x32_bf16(kA0, qf[j][0], Sa, 0, 0, 0);\
        Sa = __builtin_amdgcn_mfma_f32_16x16x32_bf16(kA1, qf[j][1], Sa, 0, 0, 0);\
        Sb = __builtin_amdgcn_mfma_f32_16x16x32_bf16(kB0, qf[j][0], Sb, 0, 0, 0);\
        Sb = __builtin_amdgcn_mfma_f32_16x16x32_bf16(kB1, qf[j][1], Sb, 0, 0, 0);\
        __builtin_amdgcn_s_setprio(0);                                           \
        float p0 = __builtin_amdgcn_exp2f(Sa[0]);                                \
        float p1 = __builtin_amdgcn_exp2f(Sa[1]);                                \
        float p2 = __builtin_amdgcn_exp2f(Sa[2]);                                \
        float p3 = __builtin_amdgcn_exp2f(Sa[3]);                                \
        float p4 = __builtin_amdgcn_exp2f(Sb[0]);                                \
        float p5 = __builtin_amdgcn_exp2f(Sb[1]);                                \
        float p6 = __builtin_amdgcn_exp2f(Sb[2]);                                \
        float p7 = __builtin_amdgcn_exp2f(Sb[3]);                                \
        union { unsigned u[4]; s16x8 v; } pk;                                    \
        asm("v_cvt_pk_bf16_f32 %0, %1, %2" : "=v"(pk.u[0]) : "v"(p0), "v"(p1));  \
        asm("v_cvt_pk_bf16_f32 %0, %1, %2" : "=v"(pk.u[1]) : "v"(p2), "v"(p3));  \
        asm("v_cvt_pk_bf16_f32 %0, %1, %2" : "=v"(pk.u[2]) : "v"(p4), "v"(p5));  \
        asm("v_cvt_pk_bf16_f32 %0, %1, %2" : "=v"(pk.u[3]) : "v"(p6), "v"(p7));  \
        __builtin_amdgcn_s_setprio(1);                                           \
        Lacc[j] = __builtin_amdgcn_mfma_f32_16x16x32_bf16(pk.v, ones, Lacc[j],   \
                                                          0, 0, 0);              \
        for (int dt = 0; dt < 4; dt++)                                           \
          O[j][dt] = __builtin_amdgcn_mfma_f32_16x16x32_bf16(pk.v, vf[dt],       \
                                                             O[j][dt], 0, 0, 0); \
        __builtin_amdgcn_s_setprio(0);                                           \
      }                                                                          \
    }                                                                            \
  } while (0)

  STAGE_KV(0);
  for (int kt2 = 0; kt2 < 16; kt2++) {
    __syncthreads();   // buf0's loads visible; all waves done reading buf1
    STAGE_KV(1);       // tile 2*kt2+1 (always valid)
    COMPUTE(0);        // tile 2*kt2
    __syncthreads();   // buf1's loads visible; all waves done reading buf0
    if (kt2 < 15) STAGE_KV(0);  // tile 2*kt2+2
    COMPUTE(1);        // tile 2*kt2+1
  }
#undef STAGE_KV
#undef COMPUTE

  // epilogue: Lacc rows align with O rows -> no cross-lane traffic
  for (int j = 0; j < 2; j++) {
    for (int r = 0; r < 4; r++) {
      float inv = 1.f / Lacc[j][r];
      int row = b * T + q0 + w * 32 + j * 16 + quad * 4 + r;
      for (int dt = 0; dt < 4; dt++) {
        int col = h * 64 + dt * 16 + lr;
        y[(size_t)row * 1024 + col] = f2bf(O[j][dt][r] * inv);
      }
    }
  }
}

// ---------------- launch ----------------

extern "C" void kernel_launch(void* const* d_in, const int* in_sizes, int n_in,
                              void* d_out, int out_size, void* d_ws, size_t ws_size,
                              hipStream_t stream) {
  const float* x  = (const float*)d_in[0];
  const float* Wa = (const float*)d_in[1];
  const float* ba = (const float*)d_in[2];
  const float* Wp = (const float*)d_in[3];
  const float* bp = (const float*)d_in[4];
  float* out = (float*)d_out;

  char* ws = (char*)d_ws;
  unsigned short* xb  = (unsigned short*)ws;                 // 16 MB: x bf16, later y
  unsigned short* Wat = (unsigned short*)(ws + 16777216);    // 6 MB
  unsigned short* Wpt = (unsigned short*)(ws + 23068672);    // 2 MB
  unsigned short* qkv = (unsigned short*)(ws + 25165824);    // 48 MB (V third unused)
  unsigned short* vtr = (unsigned short*)(ws + 75497472);    // 16 MB

  // fused prep: cvt_x (8192 blocks) + Wa transpose (3072) + Wp transpose (1024)
  prep<<<12288, 256, 0, stream>>>(x, xb, Wa, Wat, Wp, Wpt);

  // x = m-tile (64 ≡ 0 mod 8): A-tiles pinned per XCD. V third goes straight
  // to vtr (transposed in-epilogue).
  gemm_bt<1><<<dim3(64, 24), 256, 0, stream>>>(xb, Wat, ba, qkv, vtr, 8192, 3072, 1024);

  attn_flash<<<1024, 256, 0, stream>>>(qkv, vtr, xb);

  gemm_bt<0><<<dim3(64, 8), 256, 0, stream>>>(xb, Wpt, bp, out, nullptr, 8192, 1024, 1024);
}